// Round 8
// baseline (191.319 us; speedup 1.0000x reference)
//
#include <hip/hip_runtime.h>
#include <hip/hip_bf16.h>
#include <math.h>

// NT-Xent loss, fused flash-style. N=8192 rows, D=256.
//   k_norm: row L2-normalize fp32 -> bf16 (ws); zero sumexp + out
//   k_sim : bf16 MFMA, exp((sim-1)/T) in-register, row+col sums via symmetry
//   k_nll : exact fp32 pos dot + per-row nll + mean via atomicAdd
//
// History (per-strip period per resident block, the governing metric):
//   R3: 64-col strips, no sym: 3.08 us/strip (k_sim 49.3)
//   R4: LDS dbuf + vmcnt(0): REGRESSED. R8: B from global: REGRESSED.
//   R5: 32-col strips, no sym: 2.95 us/strip (47.2)
//   R6/R7: + symmetry w/ PER-STRIP global csum atomics: 5.03 us/strip (41.5)
//   R9: counted vmcnt: NULL (counts still drained the atomics - they are
//       issued after STAGE, so "N newest" forces atomic completion).
//   R10: 128-tiles @ 3 waves/SIMD: 4.34 us/strip, worse (2x strip count,
//       127-way atomic contention).
//   DIAGNOSIS: the +2.1 us/strip R5->R7 is the per-strip contended global
//   atomics (up to 63 blocks RMW the same 32 addresses) whose completion
//   every wait variant re-serializes onto the critical path.
//   R11 (this): symmetry kept, atomics MOVED OFF the strip path: csum
//   accumulates in per-block LDS via ds_add_f32 (4-way max contention),
//   flushed to global ONCE PER TILE behind a raw lgkmcnt(0)+s_barrier
//   (no vmcnt drain -> STAGE stays in flight). Skeleton reverts to R5's
//   proven 2-barrier schedule, 64 rows/wave, 32-col strips, 512 balanced
//   persistent blocks.
#define N_ROWS 8192
#define D_DIM  256
#define HALF_N 4096
#define INV_T      14.285714285714286f      // 1/0.07
#define SCALE_LOG2 20.609929155556620f      // log2(e)/0.07
#define NEG_SCALE  -20.609929155556620f
#define EPSV   1e-8f

typedef __attribute__((ext_vector_type(8))) short bf16x8;   // 8 bf16 = 4 VGPR
typedef __attribute__((ext_vector_type(4))) float f32x4;

#define AS1 __attribute__((address_space(1)))
#define AS3 __attribute__((address_space(3)))

__device__ inline unsigned short f2bf(float x) {
    unsigned int u = __float_as_uint(x);
    unsigned int r = (u + 0x7fffu + ((u >> 16) & 1u)) >> 16;   // RNE
    return (unsigned short)r;
}

// ---------------- kernel 1: normalize rows, emit bf16; zero accumulators ---
__global__ __launch_bounds__(256) void k_norm(const float* __restrict__ feat,
                                              unsigned short* __restrict__ fbf,
                                              float* __restrict__ sumexp,
                                              float* __restrict__ out) {
    const int tid = threadIdx.x;
    const int gid = blockIdx.x * 256 + tid;
    if (gid < N_ROWS) sumexp[gid] = 0.f;
    if (gid == 0) out[0] = 0.f;

    const int w = tid >> 6, lane = tid & 63;
    const int row = blockIdx.x * 4 + w;              // 2048 blocks * 4 rows
    const float4 v = ((const float4*)(feat + row * D_DIM))[lane];
    float ss = v.x*v.x + v.y*v.y + v.z*v.z + v.w*v.w;
    #pragma unroll
    for (int off = 32; off; off >>= 1) ss += __shfl_xor(ss, off);
    const float scale = 1.f / fmaxf(sqrtf(ss), EPSV);
    ushort4 o;
    o.x = f2bf(v.x * scale);
    o.y = f2bf(v.y * scale);
    o.z = f2bf(v.z * scale);
    o.w = f2bf(v.w * scale);
    ((ushort4*)(fbf + row * D_DIM))[lane] = o;
}

// ---------------- kernel 2: fused sim + exp + row/col-sum (symmetric) ------
// Work unit = strip (tile tt, jt): 256 rows x 32 cols, tt over the 528
// upper-triangle 256x256 tiles (rt >= cs), jt in [0,8). 4224 strips,
// block b owns [(33b)>>2, (33(b+1))>>2) (8 or 9; spans <= 2 tiles).
// 4 waves x 64 rows; A (64x256) in regs (128 VGPR). B strip = 16 KB LDS via
// global_load_lds w=16, XOR-16B-chunk swizzle (conflict-free ds_read_b128).
// R5 schedule per strip: sync(drain DMA) -> compute -> sync(release) ->
// STAGE(next) -> epilogue. Off-diag epilogue: rsum in regs, csum into
// csumLds[256] via ds_add_f32 (NO global atomics per strip). Tile boundary:
// lgkmcnt(0)+s_barrier (raw; STAGE stays in flight), flush csumLds (1
// atomic/thread) + rsum (shfl+atomic), zero csumLds, reload A.
__global__ __launch_bounds__(256, 2) void k_sim(const unsigned short* __restrict__ fbf,
                                                float* __restrict__ sumexp) {
    __shared__ __align__(16) char Bs[16384];
    __shared__ float csumLds[256];
    const int tid  = threadIdx.x;
    const int lane = tid & 63;
    const int w    = tid >> 6;
    const int q    = lane >> 4, l15 = lane & 15;

    int g          = (33 * blockIdx.x) >> 2;          // first strip
    const int gEnd = (33 * (blockIdx.x + 1)) >> 2;    // one past last

    // decode tile of strip g: tt -> (rt, cs), rt >= cs (32 row-tiles of 256)
    const int tt0 = g >> 3;
    int rt = (int)((sqrtf(8.f * (float)tt0 + 1.f) - 1.f) * 0.5f);
    while ((rt + 1) * (rt + 2) / 2 <= tt0) ++rt;
    while (rt * (rt + 1) / 2 > tt0) --rt;
    int cs = tt0 - rt * (rt + 1) / 2;
    int jt = g & 7;

#define ADV(rt_, cs_, jt_) do {                                               \
        if (++jt_ == 8) { jt_ = 0; if (++cs_ > rt_) { cs_ = 0; ++rt_; } }     \
    } while (0)

    int nrt = rt, ncs = cs, njt = jt;                 // coords of strip g+1
    ADV(nrt, ncs, njt);

#define STAGE(colRow0) do {                                                   \
        const char* Bg_ = (const char*)fbf + (size_t)(colRow0) * 512;         \
        _Pragma("unroll")                                                     \
        for (int i_ = 0; i_ < 4; ++i_) {                                      \
            const int idx_ = i_ * 256 + tid;                                  \
            const int col_ = idx_ >> 5;                                       \
            const int cir_ = idx_ & 31;                                       \
            __builtin_amdgcn_global_load_lds(                                 \
                (const AS1 void*)(Bg_ + col_ * 512 + ((cir_ ^ (col_ & 7)) << 4)), \
                (AS3 void*)(Bs + idx_ * 16), 16, 0, 0);                       \
        }                                                                     \
    } while (0)

    bf16x8 afrag[8][4];                               // 64 rows x 256 k
#define LOAD_A(rt_) do {                                                      \
        const int rowBase_ = (rt_) * 256 + w * 64;                            \
        _Pragma("unroll")                                                     \
        for (int t_ = 0; t_ < 8; ++t_)                                        \
            _Pragma("unroll")                                                 \
            for (int ri_ = 0; ri_ < 4; ++ri_)                                 \
                afrag[t_][ri_] = *(const bf16x8*)(fbf                         \
                    + (rowBase_ + ri_*16 + l15) * D_DIM + t_*32 + q*8);       \
    } while (0)

    float rsum[4][4];
#define ZERO_RSUM() do {                                                      \
        _Pragma("unroll")                                                     \
        for (int ri_ = 0; ri_ < 4; ++ri_)                                     \
            _Pragma("unroll")                                                 \
            for (int r_ = 0; r_ < 4; ++r_) rsum[ri_][r_] = 0.f;               \
    } while (0)

#define FLUSH_RSUM(rt_) do {                                                  \
        const int rowBase_ = (rt_) * 256 + w * 64;                            \
        _Pragma("unroll")                                                     \
        for (int ri_ = 0; ri_ < 4; ++ri_)                                     \
            _Pragma("unroll")                                                 \
            for (int r_ = 0; r_ < 4; ++r_) {                                  \
                float s_ = rsum[ri_][r_];                                     \
                s_ += __shfl_xor(s_, 1);                                      \
                s_ += __shfl_xor(s_, 2);                                      \
                s_ += __shfl_xor(s_, 4);                                      \
                s_ += __shfl_xor(s_, 8);                                      \
                if (l15 == 0)                                                 \
                    atomicAdd(&sumexp[rowBase_ + ri_ * 16 + q * 4 + r_], s_); \
            }                                                                 \
    } while (0)

    // flush per-tile LDS column sums (tile cols cs*256 .. +255), then zero.
    // Caller must have a barrier between the waves' ds_adds and this.
#define FLUSH_CSUM(cs_) do {                                                  \
        atomicAdd(&sumexp[(cs_) * 256 + tid], csumLds[tid]);                  \
        csumLds[tid] = 0.f;                                                   \
    } while (0)

    // prologue: stage strip g, load A, zero accumulators
    STAGE(cs * 256 + jt * 32);
    LOAD_A(rt);
    ZERO_RSUM();
    csumLds[tid] = 0.f;

    while (true) {
        const int colBase = cs * 256 + jt * 32;
        const bool isDiag = (rt == cs);
        const int rowBase = rt * 256 + w * 64;

        __syncthreads();                           // DMA of strip g drained

        f32x4 acc[4][2];
        #pragma unroll
        for (int ri = 0; ri < 4; ++ri)
            #pragma unroll
            for (int ci = 0; ci < 2; ++ci) acc[ri][ci] = (f32x4){0.f, 0.f, 0.f, 0.f};

        #pragma unroll
        for (int t = 0; t < 8; ++t) {
            bf16x8 bfrag[2];
            #pragma unroll
            for (int ci = 0; ci < 2; ++ci) {
                const int c   = ci * 16 + l15;     // local col 0..31
                const int cir = t * 4 + q;         // k-chunk
                bfrag[ci] = *(const bf16x8*)(Bs + c * 512 + ((cir ^ (c & 7)) << 4));
            }
            #pragma unroll
            for (int ri = 0; ri < 4; ++ri)
                #pragma unroll
                for (int ci = 0; ci < 2; ++ci)
                    acc[ri][ci] = __builtin_amdgcn_mfma_f32_16x16x32_bf16(
                        afrag[t][ri], bfrag[ci], acc[ri][ci], 0, 0, 0);
        }

        // advance coordinates; stage next strip so DMA overlaps the epilogue
        const bool more = (g + 1 < gEnd);
        if (more) {
            __syncthreads();                       // all waves done reading Bs
            STAGE(ncs * 256 + njt * 32);
        }

        // epilogue: e = exp2(acc*S - S). C/D layout: col=l15, row=q*4+reg.
        if (isDiag) {
            #pragma unroll
            for (int ri = 0; ri < 4; ++ri) {
                const int trow = rowBase + ri * 16;
                #pragma unroll
                for (int ci = 0; ci < 2; ++ci) {
                    const int tcol = colBase + ci * 16;
                    if (trow == tcol) {            // diagonal 16x16 tile
                        #pragma unroll
                        for (int r = 0; r < 4; ++r) {
                            const float e = __builtin_amdgcn_exp2f(
                                __builtin_fmaf(acc[ri][ci][r], SCALE_LOG2, NEG_SCALE));
                            rsum[ri][r] += (q * 4 + r == l15) ? 0.f : e;
                        }
                    } else {
                        #pragma unroll
                        for (int r = 0; r < 4; ++r)
                            rsum[ri][r] += __builtin_amdgcn_exp2f(
                                __builtin_fmaf(acc[ri][ci][r], SCALE_LOG2, NEG_SCALE));
                    }
                }
            }
        } else {
            // off-diagonal (rt > cs): rsum (regs) + csum into LDS (ds_add,
            // 4-way max contention over q -- NO global atomics here)
            float csA = 0.f, csB = 0.f;
            #pragma unroll
            for (int ri = 0; ri < 4; ++ri) {
                #pragma unroll
                for (int r = 0; r < 4; ++r) {
                    const float e0 = __builtin_amdgcn_exp2f(
                        __builtin_fmaf(acc[ri][0][r], SCALE_LOG2, NEG_SCALE));
                    const float e1 = __builtin_amdgcn_exp2f(
                        __builtin_fmaf(acc[ri][1][r], SCALE_LOG2, NEG_SCALE));
                    rsum[ri][r] += e0 + e1;
                    csA += e0;
                    csB += e1;
                }
            }
            atomicAdd(&csumLds[jt * 32      + l15], csA);
            atomicAdd(&csumLds[jt * 32 + 16 + l15], csB);
        }

        if (!more) break;
        if (njt == 0) {                            // crossed a tile boundary
            // all waves' ds_adds for the old tile must land before the
            // flush; raw barrier (no vmcnt drain -> STAGE stays in flight)
            asm volatile("s_waitcnt lgkmcnt(0)" ::: "memory");
            __builtin_amdgcn_s_barrier();
            __builtin_amdgcn_sched_barrier(0);
            if (!isDiag) FLUSH_CSUM(cs);           // diag tiles never added
            FLUSH_RSUM(rt);
            ZERO_RSUM();
            LOAD_A(nrt);
        }
        rt = nrt; cs = ncs; jt = njt; ++g;
    }

    // tail: flush the last (possibly partial) tile
    asm volatile("s_waitcnt lgkmcnt(0)" ::: "memory");
    __builtin_amdgcn_s_barrier();
    __builtin_amdgcn_sched_barrier(0);
    if (rt != cs) FLUSH_CSUM(cs);
    FLUSH_RSUM(rt);
#undef ADV
#undef STAGE
#undef LOAD_A
#undef ZERO_RSUM
#undef FLUSH_RSUM
#undef FLUSH_CSUM
}

// ---------------- kernel 3: exact pos similarity + nll + mean --------------
__global__ __launch_bounds__(256) void k_nll(const float* __restrict__ feat,
                                             const float* __restrict__ sumexp,
                                             float* __restrict__ out) {
    __shared__ float red[4];
    const int tid = threadIdx.x, w = tid >> 6, lane = tid & 63;
    const int i  = blockIdx.x * 4 + w;
    const int pc = (i + HALF_N) & (N_ROWS - 1);
    const float4 a = ((const float4*)(feat + i  * D_DIM))[lane];
    const float4 b = ((const float4*)(feat + pc * D_DIM))[lane];
    float dab = a.x*b.x + a.y*b.y + a.z*b.z + a.w*b.w;
    float daa = a.x*a.x + a.y*a.y + a.z*a.z + a.w*a.w;
    float dbb = b.x*b.x + b.y*b.y + b.z*b.z + b.w*b.w;
    #pragma unroll
    for (int off = 32; off; off >>= 1) {
        dab += __shfl_xor(dab, off);
        daa += __shfl_xor(daa, off);
        dbb += __shfl_xor(dbb, off);
    }
    if (lane == 0) {
        const float pos = dab / (fmaxf(sqrtf(daa), EPSV) * fmaxf(sqrtf(dbb), EPSV));
        red[w] = INV_T + logf(sumexp[i]) - pos * INV_T;
    }
    __syncthreads();
    if (tid == 0)
        atomicAdd(out, (red[0] + red[1] + red[2] + red[3]) * (1.f / N_ROWS));
}

extern "C" void kernel_launch(void* const* d_in, const int* in_sizes, int n_in,
                              void* d_out, int out_size, void* d_ws, size_t ws_size,
                              hipStream_t stream) {
    const float* feat = (const float*)d_in[0];
    char* ws = (char*)d_ws;
    unsigned short* fbf = (unsigned short*)ws;                 // 4 MB bf16
    float* sumexp = (float*)(ws + 4u * 1024u * 1024u);         // 32 KB

    k_norm<<<N_ROWS / 4, 256, 0, stream>>>(feat, fbf, sumexp, (float*)d_out);
    k_sim <<<512,        256, 0, stream>>>(fbf, sumexp);
    k_nll <<<N_ROWS / 4, 256, 0, stream>>>(feat, sumexp, (float*)d_out);
}